// Round 7
// baseline (314.392 us; speedup 1.0000x reference)
//
#include <hip/hip_runtime.h>

// Adder v8: v1/v7 structure (proven best: scalar one-shot, one wave per row,
// 256-thread blocks) with ONE change: non-temporal LOADS on a and b.
//
// Discriminating experiment. FETCH_SIZE has been pinned at 131083 KB
// (exactly half the 256 MiB read) across five structurally different
// kernels. Either (a) gfx950 TCC read counting undercounts 2x and true
// traffic is 402 MB all-HBM at 3.9 TB/s (pattern-efficiency wall), or
// (b) half the reads genuinely hit L3 and HBM is only 41% utilized, with
// the wall being the scattered miss/write interleave. nt loads mark the
// read streams no-allocate: under (b) FETCH doubles and perf moves; under
// (a) nothing changes and the roofline case is complete.
//
// Carry chain (unchanged, verified): g=(s>=10), p=(s==9) mutually
// exclusive; LSB-first C = ((P|G)+G) ^ (P|G) ^ G. Digits exact in fp32.

__global__ __launch_bounds__(256) void adder_kernel(
    const float* __restrict__ a,
    const float* __restrict__ b,
    float* __restrict__ out,
    long long n_rows)
{
    const int lane = (int)(threadIdx.x & 63);
    const long long row = (long long)blockIdx.x * 4 + (threadIdx.x >> 6);
    if (row >= n_rows) return;

    const long long idx = row * 64 + lane;   // wave: 256B contiguous
    const float av = __builtin_nontemporal_load(&a[idx]);
    const float bv = __builtin_nontemporal_load(&b[idx]);
    const float s = av + bv;                 // 0..18, exact integer

    // lane-space masks (bit l = lane l = digit index l; index 63 is LSB)
    const unsigned long long g_l = __ballot(s >= 10.0f);
    const unsigned long long p_l = __ballot(s == 9.0f);

    // reverse into LSB-first position space (position k = 63 - lane)
    const unsigned long long G  = __brevll(g_l);
    const unsigned long long P  = __brevll(p_l);
    const unsigned long long PG = P | G;
    const unsigned long long C_pos = (PG + G) ^ PG ^ G;  // carry-in per position
    const unsigned long long C_l   = __brevll(C_pos);    // back to lane space

    const float cin = (float)((C_l >> lane) & 1ULL);
    const float u = s + cin;                  // 0..19
    const float carry_out = (u >= 10.0f) ? 1.0f : 0.0f;
    out[idx] = u - 10.0f * carry_out;
}

extern "C" void kernel_launch(void* const* d_in, const int* in_sizes, int n_in,
                              void* d_out, int out_size, void* d_ws, size_t ws_size,
                              hipStream_t stream) {
    const float* a = (const float*)d_in[0];
    const float* b = (const float*)d_in[1];
    float* out = (float*)d_out;

    const long long n_rows = (long long)in_sizes[0] / 64;  // 524288
    // 256 threads = 4 waves = 4 rows per block
    const int blocks = (int)((n_rows + 3) / 4);
    adder_kernel<<<blocks, 256, 0, stream>>>(a, b, out, n_rows);
}

// Round 8
// 307.395 us; speedup vs baseline: 1.0228x; 1.0228x over previous
//
#include <hip/hip_runtime.h>

// Adder FINAL = v1/v7 (best measured: ~102 us/dispatch, 307.8 us harness).
//
// Session evidence (8 rounds, 6 passing structural variants):
//  - scalar one-shot (this):        102 us dispatch, 307.8-309.9 harness  BEST
//  - float4 grid-stride:            115 us, 318.3
//  - float4 x4 burst one-shot:      107 us, 309.8
//  - + nt stores:                   122 us, 321.1  (L3 not bypassable; FETCH unmoved)
//  - depth-2 pipelined grid-stride: 110 us, 314.5
//  - + nt loads:                     88.5 us, 314.4 (dispatch -13% but loses
//        cross-replay L2/L3 input reuse in the timed graph -> harness +6)
// Traffic is exactly minimal and invariant across all variants (FETCH
// 131083 KB / WRITE 131072 KB); VALUBusy <= 23%; zero LDS conflicts.
// The harness fits harness ~= 0.55*dispatch + 253 us; with minimal traffic
// and a structure-invariant dispatch plateau, this is the floor.
//
// Structure: one wave (64 lanes) per 64-digit row, scalar dword access,
// one-shot waves (524288 waves = max request-stream parallelism).
// Carry chain in closed form via ballot + 64-bit carry-lookahead:
//   g = (s >= 10) generate, p = (s == 9) propagate (mutually exclusive)
//   LSB-first: C = ((P|G)+G) ^ (P|G) ^ G  (adder identity for
//   c_{i+1} = g_i | (p_i & c_i)). Digits are exact small ints in fp32.

__global__ __launch_bounds__(256) void adder_kernel(
    const float* __restrict__ a,
    const float* __restrict__ b,
    float* __restrict__ out,
    long long n_rows)
{
    const int lane = (int)(threadIdx.x & 63);
    const long long row = (long long)blockIdx.x * 4 + (threadIdx.x >> 6);
    if (row >= n_rows) return;

    const long long idx = row * 64 + lane;   // wave: 256B contiguous
    const float s = a[idx] + b[idx];         // 0..18, exact integer

    // lane-space masks (bit l = lane l = digit index l; index 63 is LSB)
    const unsigned long long g_l = __ballot(s >= 10.0f);
    const unsigned long long p_l = __ballot(s == 9.0f);

    // reverse into LSB-first position space (position k = 63 - lane)
    const unsigned long long G  = __brevll(g_l);
    const unsigned long long P  = __brevll(p_l);
    const unsigned long long PG = P | G;
    const unsigned long long C_pos = (PG + G) ^ PG ^ G;  // carry-in per position
    const unsigned long long C_l   = __brevll(C_pos);    // back to lane space

    const float cin = (float)((C_l >> lane) & 1ULL);
    const float u = s + cin;                  // 0..19
    const float carry_out = (u >= 10.0f) ? 1.0f : 0.0f;
    out[idx] = u - 10.0f * carry_out;
}

extern "C" void kernel_launch(void* const* d_in, const int* in_sizes, int n_in,
                              void* d_out, int out_size, void* d_ws, size_t ws_size,
                              hipStream_t stream) {
    const float* a = (const float*)d_in[0];
    const float* b = (const float*)d_in[1];
    float* out = (float*)d_out;

    const long long n_rows = (long long)in_sizes[0] / 64;  // 524288
    // 256 threads = 4 waves = 4 rows per block
    const int blocks = (int)((n_rows + 3) / 4);
    adder_kernel<<<blocks, 256, 0, stream>>>(a, b, out, n_rows);
}